// Round 10
// baseline (182.457 us; speedup 1.0000x reference)
//
#include <hip/hip_runtime.h>

#define IH 640
#define IW 640
#define CROPSZ 512
#define NGRID 8
#define TILE 64          // CROPSZ / NGRID
#define NBINS 256
#define TP (TILE*TILE)   // 4096 pixels per tile
// clip_val = max(0.8 * 4096 / 256, 1.0) = 12.8
#define CLIPV 12.8f

typedef float fvec4 __attribute__((ext_vector_type(4)));

// ---------------------------------------------------------------------------
// Kernel 1: per-(batch,tile) histogram -> clip/redistribute -> cumsum LUT.
// Histogram is order-independent; flips map the tile onto a mirrored
// contiguous block in input space -> plain forward 64x64 block, vec4 loads.
// One 256-thread block per (batch,tile). 4096 blocks.
// ---------------------------------------------------------------------------
__global__ __launch_bounds__(256) void clahe_lut_kernel(
    const float* __restrict__ x,
    const int* __restrict__ hflip, const int* __restrict__ vflip,
    const int* __restrict__ offy,  const int* __restrict__ offx,
    const int* __restrict__ apply,
    float* __restrict__ luts)
{
    const int bt = blockIdx.x;         // b*64 + tile  (scalar)
    const int b  = bt >> 6;
    if (!apply[b]) return;             // wave-uniform; LUT never read for these
    const int tile = bt & 63;
    const int tyi = tile >> 3, txi = tile & 7;

    const int oy = offy[b], ox = offx[b];
    const int by = tyi * TILE, bx = txi * TILE;
    const int sy = vflip[b] ? (IH - TILE - oy - by) : (oy + by);
    const int sx = hflip[b] ? (IW - TILE - ox - bx) : (ox + bx);

    __shared__ unsigned int hist[4][NBINS];   // per-wave sub-histograms
    const int t    = threadIdx.x;
    const int lane = t & 63;
    const int wid  = t >> 6;
    #pragma unroll
    for (int w = 0; w < 4; ++w) hist[w][t] = 0u;
    __syncthreads();

    const float* __restrict__ xb = x + (size_t)b * (IH * IW);

    // regular (cache-allocating) loads: k2 re-reads this exact region; input
    // fits in L3 (100 MiB < 256 MiB) so seed the cache for it.
    #pragma unroll
    for (int k = 0; k < 4; ++k) {
        const int q    = t + k * 256;
        const int row  = q >> 4;
        const int col4 = (q & 15) << 2;
        const fvec4 v = *reinterpret_cast<const fvec4*>(
            xb + (size_t)(sy + row) * IW + sx + col4);
        #pragma unroll
        for (int j = 0; j < 4; ++j) {
            int bin = (int)(v[j] * 256.0f);
            bin = bin < 0 ? 0 : (bin > 255 ? 255 : bin);
            atomicAdd(&hist[wid][bin], 1u);
        }
    }
    __syncthreads();

    const float h = (float)(hist[0][t] + hist[1][t] + hist[2][t] + hist[3][t]);
    const float clipped = fminf(h, CLIPV);
    float ex = h - clipped;

    #pragma unroll
    for (int off = 32; off > 0; off >>= 1) ex += __shfl_down(ex, off, 64);
    __shared__ float wsum[4];
    if (lane == 0) wsum[wid] = ex;
    __syncthreads();
    const float excess = wsum[0] + wsum[1] + wsum[2] + wsum[3];

    const float hv = clipped + excess * (1.0f / (float)NBINS);

    float s = hv;
    #pragma unroll
    for (int off = 1; off < 64; off <<= 1) {
        const float n = __shfl_up(s, off, 64);
        if (lane >= off) s += n;
    }
    __shared__ float wtot[4];
    if (lane == 63) wtot[wid] = s;
    __syncthreads();
    float prefix = 0.0f;
    for (int w = 0; w < wid; ++w) prefix += wtot[w];
    s += prefix;

    float lut = s * (255.0f / (float)TP);
    lut = fminf(fmaxf(lut, 0.0f), 255.0f);
    luts[(size_t)bt * NBINS + t] = lut;
}

// ---------------------------------------------------------------------------
// Kernel 2: output. Block = 64x64 region of one image (1024 threads, 4 px
// each). 4 quad-LUTs staged in LDS as SoA (4 separate float planes) so the
// random-bin reads are 4x ds_read_b32 spread over all 32 banks (~2-way
// aliasing = free) instead of one b128 over 8 bank-groups.
// 64 blocks per image, 4096 total.
// ---------------------------------------------------------------------------
__global__ __launch_bounds__(1024) void augment_out_kernel(
    const float* __restrict__ x,
    const int* __restrict__ hflip, const int* __restrict__ vflip,
    const int* __restrict__ offy,  const int* __restrict__ offx,
    const int* __restrict__ apply,
    const float* __restrict__ luts,
    float* __restrict__ out)
{
    const int bid  = blockIdx.x;
    const int b    = bid >> 6;           // 64 blocks / image (scalar)
    const int blk  = bid & 63;
    const int cbig = blk & 7;            // 64-wide col stripe
    const int rbig = blk >> 3;           // 64-tall row stripe

    const int t  = threadIdx.x;
    const int tc = t & 15;               // col group of 4 within stripe
    const int r  = t >> 4;               // row within stripe [0,64)

    const int y   = rbig * 64 + r;
    const int col = cbig * 64 + tc * 4;  // first of 4 output cols

    const int hf = hflip[b], vf = vflip[b];
    const int oy = offy[b],  ox = offx[b];
    const int ap = apply[b];

    const int iy = vf ? (IH - 1 - oy - y) : (oy + y);
    const float* __restrict__ row = x + (size_t)b * (IH * IW) + (size_t)iy * IW;

    fvec4 v;
    if (hf) {
        const fvec4 rr = *reinterpret_cast<const fvec4*>(row + (IW - 4 - ox - col));
        v = (fvec4){rr.w, rr.z, rr.y, rr.x};
    } else {
        v = *reinterpret_cast<const fvec4*>(row + ox + col);
    }

    fvec4 o;
    if (ap) {                            // block-uniform branch
        // SoA: plane p of table tab at lut_s[p][tab*256 + bin]
        __shared__ float lut_s[4][4 * NBINS];   // 16 KiB

        // stage: one (tab,bin) per thread (1024 = 4 tables * 256 bins)
        {
            const int tab = t >> 8;      // 0..3
            const int bin = t & 255;
            const int hy  = tab >> 1, hx = tab & 1;
            const int y0  = max(0, min(NGRID - 1, rbig - 1 + hy));
            const int y1  = max(0, min(NGRID - 1, rbig     + hy));
            const int x0  = max(0, min(NGRID - 1, cbig - 1 + hx));
            const int x1  = max(0, min(NGRID - 1, cbig     + hx));
            const float* __restrict__ lb = luts + (size_t)b * (64 * NBINS);
            lut_s[0][t] = lb[((y0 << 3) + x0) * NBINS + bin];
            lut_s[1][t] = lb[((y0 << 3) + x1) * NBINS + bin];
            lut_s[2][t] = lb[((y1 << 3) + x0) * NBINS + bin];
            lut_s[3][t] = lb[((y1 << 3) + x1) * NBINS + bin];
        }
        __syncthreads();

        const int hy  = r >> 5;          // wave-uniform
        const int hx  = tc >> 3;         // per-lane, uniform over j
        const int tbase = ((hy << 1) + hx) << 8;   // tab*256
        const float fy  = (y + 0.5f) * (1.0f / TILE) - 0.5f - (float)(rbig - 1 + hy);
        const float fx0 = (col + 0.5f) * (1.0f / TILE) - 0.5f - (float)(cbig - 1 + hx);

        #pragma unroll
        for (int j = 0; j < 4; ++j) {
            const float fx = fx0 + j * (1.0f / TILE);
            int bin = (int)(v[j] * 256.0f);
            bin = bin < 0 ? 0 : (bin > 255 ? 255 : bin);
            const int a = tbase + bin;
            const float v00 = lut_s[0][a];
            const float v01 = lut_s[1][a];
            const float v10 = lut_s[2][a];
            const float v11 = lut_s[3][a];
            const float top = (1.0f - fx) * v00 + fx * v01;
            const float bot = (1.0f - fx) * v10 + fx * v11;
            o[j] = ((1.0f - fy) * top + fy * bot) * (1.0f / 255.0f);
        }
    } else {
        o = v;
    }

    const size_t oidx = (size_t)b * (CROPSZ * CROPSZ / 4) + (size_t)y * (CROPSZ / 4) + (col >> 2);
    __builtin_nontemporal_store(o, reinterpret_cast<fvec4*>(out) + oidx);
}

// ---------------------------------------------------------------------------
extern "C" void kernel_launch(void* const* d_in, const int* in_sizes, int n_in,
                              void* d_out, int out_size, void* d_ws, size_t ws_size,
                              hipStream_t stream) {
    const float* x     = (const float*)d_in[0];
    const int*   hflip = (const int*)d_in[1];
    const int*   vflip = (const int*)d_in[2];
    const int*   offy  = (const int*)d_in[3];
    const int*   offx  = (const int*)d_in[4];
    const int*   apply = (const int*)d_in[5];
    float*       out   = (float*)d_out;
    float*       luts  = (float*)d_ws;   // 64*64*256*4 B = 4 MiB

    hipLaunchKernelGGL(clahe_lut_kernel, dim3(64 * 64), dim3(256), 0, stream,
                       x, hflip, vflip, offy, offx, apply, luts);

    hipLaunchKernelGGL(augment_out_kernel, dim3(64 * 64), dim3(1024), 0, stream,
                       x, hflip, vflip, offy, offx, apply, luts, out);
}